// Round 4
// baseline (582.464 us; speedup 1.0000x reference)
//
#include <hip/hip_runtime.h>
#include <hip/hip_fp16.h>

#define NEG (-1e30f)

// B=2048, T=256, C=128, L=32, S=65. Fused: 512 blocks x 256 thr,
// wave w of block g owns batch row r = g*4+w end-to-end.
// Phase 1: 8 lanes per t-row -> full-128B-line loads, 4KB/wave working set.
// Phase 2: DPP wave_shr recursion (R3, verified).
// lp in LDS as fp16 (ulp ~1e-3 at |x|<16; 255-step accum err ~0.3 << 23.4).

__device__ __forceinline__ float dpp_shr1_neg(float x) {
    // whole-wave shift right by 1; lane 0 <- NEG
    return __int_as_float(__builtin_amdgcn_update_dpp(
        __float_as_int(NEG), __float_as_int(x), 0x138, 0xF, 0xF, false));
}
__device__ __forceinline__ float quad_xor1_add(float x) {  // quad_perm [1,0,3,2]
    return x + __int_as_float(__builtin_amdgcn_update_dpp(
        0, __float_as_int(x), 0xB1, 0xF, 0xF, true));
}
__device__ __forceinline__ float quad_xor2_add(float x) {  // quad_perm [2,3,0,1]
    return x + __int_as_float(__builtin_amdgcn_update_dpp(
        0, __float_as_int(x), 0x4E, 0xF, 0xF, true));
}
__device__ __forceinline__ float half_mirror_add(float x) { // row_half_mirror
    return x + __int_as_float(__builtin_amdgcn_update_dpp(
        0, __float_as_int(x), 0x141, 0xF, 0xF, true));
}

__global__ __launch_bounds__(256, 2) void ctc_fused_kernel(
    const int* __restrict__ y_true,    // [2048,32]
    const float* __restrict__ y_pred,  // [2048,256,128]
    float* __restrict__ out)           // [2048]
{
    __shared__ __half lp[4][256][34];  // [wave][t][j] j=0 blank, 1..32 labels
    __shared__ int labs[4][32];

    const int tid  = threadIdx.x;
    const int wave = tid >> 6;
    const int lane = tid & 63;
    const int r    = blockIdx.x * 4 + wave;

    if (lane < 32) labs[wave][lane] = y_true[r * 32 + lane];
    __syncthreads();

    const float* __restrict__ Y = y_pred + (size_t)r * 256 * 128;

    // ---- Phase 1: softmax denom + gather. 8 lanes per row, 8 rows per iter ----
    const int row8 = lane >> 3;   // 0..7 : which row of the 8-row slab
    const int q    = lane & 7;    // 0..7 : position within the row's 32 float4s

    for (int it = 0; it < 32; ++it) {
        const int t = it * 8 + row8;
        const float4* __restrict__ rp = (const float4*)(Y + (size_t)t * 128);
        // lane covers classes {4q..4q+3} + 32*j  -> row tiled contiguously
        float4 v0 = rp[q];
        float4 v1 = rp[q + 8];
        float4 v2 = rp[q + 16];
        float4 v3 = rp[q + 24];
        float a0 = __expf(v0.x) + __expf(v1.x) + __expf(v2.x) + __expf(v3.x);
        float a1 = __expf(v0.y) + __expf(v1.y) + __expf(v2.y) + __expf(v3.y);
        float a2 = __expf(v0.z) + __expf(v1.z) + __expf(v2.z) + __expf(v3.z);
        float a3 = __expf(v0.w) + __expf(v1.w) + __expf(v2.w) + __expf(v3.w);
        float se = (a0 + a1) + (a2 + a3);
        se = quad_xor1_add(se);        // sum over lane^1
        se = quad_xor2_add(se);        // sum over lane^2
        se = half_mirror_add(se);      // sum over the 8-lane group
        const float lse = __logf(se);

        // gather blank + 32 labels; lane q takes j = q, q+8, ... (L1-hit loads)
        #pragma unroll
        for (int jj = 0; jj < 5; ++jj) {
            const int j = q + jj * 8;
            if (j < 33) {
                const int c = (j == 0) ? 0 : labs[wave][j - 1];
                lp[wave][t][j] = __float2half(Y[(size_t)t * 128 + c] - lse);
            }
        }
    }
    __syncthreads();

    // ---- Phase 2: forward recursion, lane s = state 0..63; a64 in lane 63 ----
    {
        const int s  = lane;
        const int hi = s >> 1;
        const int li = labs[wave][hi];
        const int lm = (hi >= 1) ? labs[wave][hi - 1] : 0;
        const bool can_skip = (s & 1) && (s >= 3) && (li != lm);
        const int  lpidx    = (s & 1) ? (1 + hi) : 0;
        const __half* P = &lp[wave][0][0];

        float alpha = (s == 0) ? __half2float(P[0]) :
                      (s == 1) ? __half2float(P[1]) : NEG;
        float a64 = NEG;   // alpha[64]; only lane 63's copy is meaningful

        #pragma unroll 4
        for (int t = 1; t < 256; ++t) {
            const float lpv = __half2float(P[t * 34 + lpidx]);
            const float lp0 = __half2float(P[t * 34]);

            // alpha[64] = logaddexp(a64, old alpha[63]) + lp(blank)
            float m2   = fmaxf(a64, alpha);
            float a64n = m2 + __logf(__expf(a64 - m2) + __expf(alpha - m2)) + lp0;

            float b1 = dpp_shr1_neg(alpha);    // alpha[s-1], NEG into s=0
            float b2 = dpp_shr1_neg(b1);       // alpha[s-2], NEG into s=0,1
            if (!can_skip) b2 = NEG;
            float m = fmaxf(fmaxf(alpha, b1), b2);
            alpha = m + __logf(__expf(alpha - m) + __expf(b1 - m) + __expf(b2 - m)) + lpv;
            a64 = a64n;
        }

        if (s == 63) {
            float m = fmaxf(alpha, a64);
            out[r] = -(m + __logf(__expf(alpha - m) + __expf(a64 - m)));
        }
    }
}

extern "C" void kernel_launch(void* const* d_in, const int* in_sizes, int n_in,
                              void* d_out, int out_size, void* d_ws, size_t ws_size,
                              hipStream_t stream) {
    const int*   y_true = (const int*)d_in[0];
    const float* y_pred = (const float*)d_in[1];
    float*       out    = (float*)d_out;
    ctc_fused_kernel<<<512, 256, 0, stream>>>(y_true, y_pred, out);
}